// Round 10
// baseline (90.662 us; speedup 1.0000x reference)
//
#include <hip/hip_runtime.h>
#include <math.h>

#define NB 16
#define NL 4096
#define NC 512
#define NC4 128          // NC/4 float4 per row
#define NKEEP 2458       // ceil(4096*0.6)
#define KEEPB 76         // first k_perm block with tail rows (76*32 = 2432)
#define NTAILB 52        // 128 - 76 partial slots per batch

typedef float f32x4 __attribute__((ext_vector_type(4)));

// ---------------- ws layout ----------------
// wp      f32 [NB][NL]        @ 0        (256 KB) rank-indexed unnormalized exp (0 for p<NKEEP)
// order   i32 [NB][NL]        @ 262144   (256 KB) inverse permutation (src row per rank)
// partial f32 [NB][52][512]   @ 524288   (1.66 MB)
// Zpart   f32 [16]            @ 2359296

// Kernel 1: one block per batch. Wave 0: bit-exact np pairwise mean
// (PW_BLOCKSIZE=128, 8-acc base, butterfly combine) -> alpha/beta. All 1024
// threads build the 4096 composite keys (mul,mul,add, no FMA; sortable-uint
// map is an involution -> score decodable bit-exactly) in LDS, full bitonic
// sort ascending (descending score, stable via index tiebreak). Sorted
// position p == rank: emit order[p], rank-indexed w, scattered mask, Z.
__global__ void __launch_bounds__(1024) k_sortmid(const float* __restrict__ ax,
                                                  const float* __restrict__ ay,
                                                  float* __restrict__ wp,
                                                  float* __restrict__ mask_out,
                                                  int* __restrict__ order,
                                                  float* __restrict__ Zpart) {
  __shared__ unsigned long long lsk[4096];   // 32 KB
  __shared__ float s_ab[2];
  __shared__ float zred[16];
  int b = blockIdx.x;
  int t = threadIdx.x;

  if (t < 64) {
    int lane = t;
    float sx = 0.0f, sy = 0.0f;
    if (lane < 32) {
      const float* px = ax + b * NL + lane * 128;
      const float* py = ay + b * NL + lane * 128;
      float r[8], q[8];
#pragma unroll
      for (int j = 0; j < 8; ++j) { r[j] = px[j]; q[j] = py[j]; }
      for (int i = 8; i < 128; i += 8) {
#pragma unroll
        for (int j = 0; j < 8; ++j) {
          r[j] = __fadd_rn(r[j], px[i + j]);
          q[j] = __fadd_rn(q[j], py[i + j]);
        }
      }
      sx = __fadd_rn(__fadd_rn(__fadd_rn(r[0], r[1]), __fadd_rn(r[2], r[3])),
                     __fadd_rn(__fadd_rn(r[4], r[5]), __fadd_rn(r[6], r[7])));
      sy = __fadd_rn(__fadd_rn(__fadd_rn(q[0], q[1]), __fadd_rn(q[2], q[3])),
                     __fadd_rn(__fadd_rn(q[4], q[5]), __fadd_rn(q[6], q[7])));
    }
#pragma unroll
    for (int m = 1; m <= 16; m <<= 1) {
      sx = __fadd_rn(sx, __shfl_xor(sx, m, 64));
      sy = __fadd_rn(sy, __shfl_xor(sy, m, 64));
    }
    if (lane == 0) {
      float mx = __fdiv_rn(sx, 4096.0f);
      float my = __fdiv_rn(sy, 4096.0f);
      float cov = __fdiv_rn(my, __fadd_rn(mx, 1e-6f));
      float z = __fsub_rn(1.0f, cov);
      double a = 1.0 / (1.0 + exp(-(double)z));   // correctly-rounded sigmoid
      float af = (float)a;
      s_ab[0] = af;
      s_ab[1] = __fsub_rn(1.0f, af);
    }
  }
  __syncthreads();
  float af = s_ab[0], bf = s_ab[1];

#pragma unroll
  for (int e = 0; e < 4; ++e) {
    int l = e * 1024 + t;
    int idx = b * NL + l;
    float s = __fadd_rn(__fmul_rn(af, ax[idx]), __fmul_rn(bf, ay[idx]));
    unsigned u = __float_as_uint(s);
    unsigned su = u ^ ((u & 0x80000000u) ? 0xFFFFFFFFu : 0x80000000u);
    lsk[l] = ((unsigned long long)(~su) << 32) | (unsigned)l;
  }
  __syncthreads();

  // bitonic sort, ascending keys == descending scores, stable (unique keys)
  for (int k = 2; k <= 4096; k <<= 1) {
    for (int j = k >> 1; j > 0; j >>= 1) {
#pragma unroll
      for (int e = 0; e < 4; ++e) {
        int i = e * 1024 + t;
        int l2 = i ^ j;
        if (l2 > i) {                      // unique owner per disjoint pair
          unsigned long long a = lsk[i], bb = lsk[l2];
          bool up = ((i & k) == 0);
          if ((a > bb) == up) { lsk[i] = bb; lsk[l2] = a; }
        }
      }
      __syncthreads();
    }
  }

  // smax = score of global best (position 0), decoded bit-exactly
  unsigned su0 = ~(unsigned)(lsk[0] >> 32);
  float smax = (su0 & 0x80000000u) ? __uint_as_float(su0 ^ 0x80000000u)
                                   : __uint_as_float(~su0);
  float zs = 0.0f;
#pragma unroll
  for (int e = 0; e < 4; ++e) {
    int p = e * 1024 + t;
    unsigned long long kk = lsk[p];
    int l = (int)(unsigned)kk;
    unsigned su = ~(unsigned)(kk >> 32);
    float s = (su & 0x80000000u) ? __uint_as_float(su ^ 0x80000000u)
                                 : __uint_as_float(~su);
    order[b * NL + p] = l;                              // coalesced
    float wi = (p >= NKEEP) ? expf(s - smax) : 0.0f;
    wp[b * NL + p] = wi;                                // coalesced, rank-indexed
    mask_out[b * NL + l] = (p < NKEEP) ? 1.0f : 0.0f;   // scattered 4B (small)
    zs += wi;
  }
#pragma unroll
  for (int d = 1; d < 64; d <<= 1) zs += __shfl_xor(zs, d, 64);
  if ((t & 63) == 0) zred[t >> 6] = zs;
  __syncthreads();
  if (t == 0) {
    float z = 0.0f;
#pragma unroll
    for (int k = 0; k < 16; ++k) z += zred[k];
    Zpart[b] = z;
  }
}

// Kernel 2: the permute, output-centric. Block owns 32 consecutive OUTPUT
// positions: gathered cached reads (16 independent loads in flight/thread),
// streaming 64 KB contiguous writes. Positions >= NKEEP accumulate
// w-weighted rows into partial slabs. grid (128, NB) x 256.
__global__ void __launch_bounds__(256) k_perm(const f32x4* __restrict__ tok,
                                              const int* __restrict__ order,
                                              const float* __restrict__ wp,
                                              f32x4* __restrict__ sel,
                                              f32x4* __restrict__ partial) {
  int b = blockIdx.y;
  int bx = blockIdx.x;
  int p0 = bx * 32;
  int tid = threadIdx.x;
  int col = tid & 127;
  int g = tid >> 7;            // rows p0+g*16 .. p0+g*16+15
  __shared__ int ssrc[32];
  __shared__ float swt[32];
  __shared__ float accsh[512];
  if (tid < 32) {
    int p = p0 + tid;
    ssrc[tid] = order[b * NL + p];
    swt[tid] = wp[b * NL + p];     // rank-indexed: contiguous, 0 for keep
  }
  __syncthreads();

  const f32x4* tb = tok + (size_t)b * NL * NC4 + col;
  f32x4 v[16];
#pragma unroll
  for (int k = 0; k < 16; ++k)
    v[k] = tb[(size_t)ssrc[g * 16 + k] * NC4];

  f32x4* sb = sel + (size_t)b * NKEEP * NC4 + col;
  float a0 = 0.f, a1 = 0.f, a2 = 0.f, a3 = 0.f;
#pragma unroll
  for (int k = 0; k < 16; ++k) {
    int p = p0 + g * 16 + k;
    if (p < NKEEP) {
      sb[(size_t)p * NC4] = v[k];          // streaming contiguous writes
    } else {
      float wk = swt[g * 16 + k];
      a0 = fmaf(wk, v[k].x, a0);
      a1 = fmaf(wk, v[k].y, a1);
      a2 = fmaf(wk, v[k].z, a2);
      a3 = fmaf(wk, v[k].w, a3);
    }
  }

  if (bx >= KEEPB) {                        // uniform per block
    if (g == 1) {
      accsh[col * 4 + 0] = a0; accsh[col * 4 + 1] = a1;
      accsh[col * 4 + 2] = a2; accsh[col * 4 + 3] = a3;
    }
    __syncthreads();
    if (g == 0) {
      f32x4 o;
      o.x = a0 + accsh[col * 4 + 0];
      o.y = a1 + accsh[col * 4 + 1];
      o.z = a2 + accsh[col * 4 + 2];
      o.w = a3 + accsh[col * 4 + 3];
      partial[(size_t)(b * NTAILB + (bx - KEEPB)) * 128 + col] = o;
    }
  }
}

// Kernel 3: extra = (sum of 52 partials) / Z. 16 x 512.
__global__ void __launch_bounds__(512) k_back(const float* __restrict__ partial,
                                              const float* __restrict__ Zpart,
                                              float* __restrict__ extra) {
  int b = blockIdx.x;
  int c = threadIdx.x;    // 0..511
  float Zb = Zpart[b];
  const float* p = partial + (size_t)b * NTAILB * 512 + c;
  float a0 = 0.f, a1 = 0.f, a2 = 0.f, a3 = 0.f;
#pragma unroll
  for (int j = 0; j < NTAILB; j += 4) {
    a0 += p[(size_t)(j + 0) * 512];
    a1 += p[(size_t)(j + 1) * 512];
    a2 += p[(size_t)(j + 2) * 512];
    a3 += p[(size_t)(j + 3) * 512];
  }
  extra[b * NC + c] = ((a0 + a1) + (a2 + a3)) / Zb;
}

extern "C" void kernel_launch(void* const* d_in, const int* in_sizes, int n_in,
                              void* d_out, int out_size, void* d_ws, size_t ws_size,
                              hipStream_t stream) {
  (void)in_sizes; (void)n_in; (void)out_size; (void)ws_size;
  const f32x4* tok = (const f32x4*)d_in[0];
  const float* ax = (const float*)d_in[1];
  const float* ay = (const float*)d_in[2];

  float* wp = (float*)d_ws;
  int* order = (int*)((char*)d_ws + 262144);
  f32x4* partial = (f32x4*)((char*)d_ws + 524288);
  float* Zpart = (float*)((char*)d_ws + 2359296);

  float* out = (float*)d_out;
  f32x4* sel = (f32x4*)out;                         // [16][2458][512]
  float* extra = out + (size_t)NB * NKEEP * NC;     // [16][1][512]
  float* mask = extra + (size_t)NB * NC;            // [16][4096]

  k_sortmid<<<NB, 1024, 0, stream>>>(ax, ay, wp, mask, order, Zpart);
  k_perm<<<dim3(128, NB), 256, 0, stream>>>(tok, order, wp, sel, partial);
  k_back<<<NB, 512, 0, stream>>>((const float*)partial, Zpart, extra);
}

// Round 11
// 63.756 us; speedup vs baseline: 1.4220x; 1.4220x over previous
//
#include <hip/hip_runtime.h>
#include <math.h>

#define NB 16
#define NL 4096
#define NC 512
#define NC4 128          // NC/4 float4 per row
#define NKEEP 2458       // ceil(4096*0.6)
#define KEEPB 76         // first k_perm block with tail rows (76*32 = 2432)
#define NTAILB 52        // 128 - 76 partial slots per batch

typedef float f32x4 __attribute__((ext_vector_type(4)));

// ---------------- ws layout ----------------
// skey    u64 [NB][8][512]    @ 0        (512 KB)  per-chunk ascending-sorted keys
// w       f32 [NB][NL]        @ 524288   (256 KB)  unnormalized exp, 0 for keep
// order   i32 [NB][NL]        @ 786432   (256 KB)  inverse permutation
// partial f32 [NB][52][512]   @ 1048576  (1.66 MB)
// Zpart   f32 [128]           @ 2883584

// Kernel 1: per-chunk sort, self-contained. Wave 0 recomputes the batch's
// alpha with the bit-exact np pairwise-mean code (deterministic, redundant
// across the batch's 8 blocks). All 256 threads then build the chunk's 512
// composite keys (mul,mul,add, no FMA) in LDS, bitonic-sort ascending
// (keys unique via index tiebreak), write skey. grid (8, NB) x 256.
__global__ void __launch_bounds__(256) k_sort(const float* __restrict__ ax,
                                              const float* __restrict__ ay,
                                              unsigned long long* __restrict__ skey) {
  __shared__ unsigned long long lk[512];
  __shared__ float s_ab[2];
  int b = blockIdx.y;
  int c = blockIdx.x;
  int t = threadIdx.x;

  if (t < 64) {
    int lane = t;
    float sx = 0.0f, sy = 0.0f;
    if (lane < 32) {
      const float* px = ax + b * NL + lane * 128;
      const float* py = ay + b * NL + lane * 128;
      float r[8], q[8];
#pragma unroll
      for (int j = 0; j < 8; ++j) { r[j] = px[j]; q[j] = py[j]; }
      for (int i = 8; i < 128; i += 8) {
#pragma unroll
        for (int j = 0; j < 8; ++j) {
          r[j] = __fadd_rn(r[j], px[i + j]);
          q[j] = __fadd_rn(q[j], py[i + j]);
        }
      }
      sx = __fadd_rn(__fadd_rn(__fadd_rn(r[0], r[1]), __fadd_rn(r[2], r[3])),
                     __fadd_rn(__fadd_rn(r[4], r[5]), __fadd_rn(r[6], r[7])));
      sy = __fadd_rn(__fadd_rn(__fadd_rn(q[0], q[1]), __fadd_rn(q[2], q[3])),
                     __fadd_rn(__fadd_rn(q[4], q[5]), __fadd_rn(q[6], q[7])));
    }
#pragma unroll
    for (int m = 1; m <= 16; m <<= 1) {
      sx = __fadd_rn(sx, __shfl_xor(sx, m, 64));
      sy = __fadd_rn(sy, __shfl_xor(sy, m, 64));
    }
    if (lane == 0) {
      float mx = __fdiv_rn(sx, 4096.0f);
      float my = __fdiv_rn(sy, 4096.0f);
      float cov = __fdiv_rn(my, __fadd_rn(mx, 1e-6f));
      float z = __fsub_rn(1.0f, cov);
      double a = 1.0 / (1.0 + exp(-(double)z));   // correctly-rounded sigmoid
      float af = (float)a;
      s_ab[0] = af;
      s_ab[1] = __fsub_rn(1.0f, af);
    }
  }
  __syncthreads();
  float af = s_ab[0], bf = s_ab[1];

#pragma unroll
  for (int e = 0; e < 2; ++e) {
    int l = c * 512 + t + e * 256;
    int idx = b * NL + l;
    float s = __fadd_rn(__fmul_rn(af, ax[idx]), __fmul_rn(bf, ay[idx]));
    unsigned u = __float_as_uint(s);
    unsigned su = u ^ ((u & 0x80000000u) ? 0xFFFFFFFFu : 0x80000000u);
    lk[t + e * 256] = ((unsigned long long)(~su) << 32) | (unsigned)l;
  }
  __syncthreads();

  for (int k = 2; k <= 512; k <<= 1) {
    for (int j = k >> 1; j > 0; j >>= 1) {
#pragma unroll
      for (int e = 0; e < 2; ++e) {
        int i = t + e * 256;
        int l = i ^ j;
        if (l > i) {                       // unique owner per disjoint pair
          unsigned long long a = lk[i], bb = lk[l];
          bool up = ((i & k) == 0);
          if ((a > bb) == up) { lk[i] = bb; lk[l] = a; }
        }
      }
      __syncthreads();
    }
  }
  unsigned long long* sb = skey + ((size_t)b * 8 + c) * 512;
  sb[t] = lk[t];
  sb[t + 256] = lk[t + 256];
}

// Kernel 2: rank via 8 branchless lower_bounds in the batch's sorted chunks
// (staged in 32 KB LDS); smax decoded from the global min key (= max score);
// mask, w = exp(s - smax), order inversion, per-block Z partial.
// grid 128 (= 8 blocks/batch) x 512.
__global__ void __launch_bounds__(512) k_mid(const float* __restrict__ ax,
                                             const float* __restrict__ ay,
                                             const unsigned long long* __restrict__ skey,
                                             float* __restrict__ w,
                                             float* __restrict__ mask_out,
                                             int* __restrict__ order,
                                             float* __restrict__ Zpart) {
  __shared__ unsigned long long lsk[4096];   // 32 KB
  __shared__ float zred[8];
  int bx = blockIdx.x;
  int b = bx >> 3;
  int q = bx & 7;
  int t = threadIdx.x;
  const unsigned long long* sb = skey + (size_t)b * NL;
#pragma unroll
  for (int k = 0; k < 8; ++k) lsk[k * 512 + t] = sb[k * 512 + t];
  __syncthreads();

  // smax = score of the global min key (keys ascend <=> scores descend)
  unsigned long long kmin = lsk[0];
#pragma unroll
  for (int c = 1; c < 8; ++c) {
    unsigned long long h = lsk[c * 512];
    kmin = (h < kmin) ? h : kmin;
  }
  unsigned su0 = ~(unsigned)(kmin >> 32);
  float smax = (su0 & 0x80000000u) ? __uint_as_float(su0 ^ 0x80000000u)
                                   : __uint_as_float(~su0);

  // recompute alpha exactly as k_sort did (deterministic, bit-identical)
  __shared__ float s_ab[2];
  if (t < 64) {
    int lane = t;
    float sx = 0.0f, sy = 0.0f;
    if (lane < 32) {
      const float* px = ax + b * NL + lane * 128;
      const float* py = ay + b * NL + lane * 128;
      float r[8], qq[8];
#pragma unroll
      for (int j = 0; j < 8; ++j) { r[j] = px[j]; qq[j] = py[j]; }
      for (int i = 8; i < 128; i += 8) {
#pragma unroll
        for (int j = 0; j < 8; ++j) {
          r[j] = __fadd_rn(r[j], px[i + j]);
          qq[j] = __fadd_rn(qq[j], py[i + j]);
        }
      }
      sx = __fadd_rn(__fadd_rn(__fadd_rn(r[0], r[1]), __fadd_rn(r[2], r[3])),
                     __fadd_rn(__fadd_rn(r[4], r[5]), __fadd_rn(r[6], r[7])));
      sy = __fadd_rn(__fadd_rn(__fadd_rn(qq[0], qq[1]), __fadd_rn(qq[2], qq[3])),
                     __fadd_rn(__fadd_rn(qq[4], qq[5]), __fadd_rn(qq[6], qq[7])));
    }
#pragma unroll
    for (int m = 1; m <= 16; m <<= 1) {
      sx = __fadd_rn(sx, __shfl_xor(sx, m, 64));
      sy = __fadd_rn(sy, __shfl_xor(sy, m, 64));
    }
    if (lane == 0) {
      float mx = __fdiv_rn(sx, 4096.0f);
      float my = __fdiv_rn(sy, 4096.0f);
      float cov = __fdiv_rn(my, __fadd_rn(mx, 1e-6f));
      float z = __fsub_rn(1.0f, cov);
      double a = 1.0 / (1.0 + exp(-(double)z));
      float af = (float)a;
      s_ab[0] = af;
      s_ab[1] = __fsub_rn(1.0f, af);
    }
  }
  __syncthreads();
  int l = q * 512 + t;
  int gid = b * NL + l;
  float s = __fadd_rn(__fmul_rn(s_ab[0], ax[gid]), __fmul_rn(s_ab[1], ay[gid]));
  unsigned u = __float_as_uint(s);
  unsigned su = u ^ ((u & 0x80000000u) ? 0xFFFFFFFFu : 0x80000000u);
  unsigned long long ki = ((unsigned long long)(~su) << 32) | (unsigned)l;

  int r = 0;
#pragma unroll
  for (int c = 0; c < 8; ++c) {
    const unsigned long long* base = lsk + c * 512;
    int pos = 0;
#pragma unroll
    for (int step = 512; step >= 1; step >>= 1) {
      int cand = pos + step;
      if (cand <= 512 && base[cand - 1] < ki) pos = cand;
    }
    r += pos;   // count of keys < ki in this chunk
  }

  mask_out[gid] = (r < NKEEP) ? 1.0f : 0.0f;
  float wi = (r >= NKEEP) ? expf(s - smax) : 0.0f;
  w[gid] = wi;
  order[b * NL + r] = l;

  float zs = wi;
#pragma unroll
  for (int d = 1; d < 64; d <<= 1) zs += __shfl_xor(zs, d, 64);
  if ((t & 63) == 0) zred[t >> 6] = zs;
  __syncthreads();
  if (t == 0) {
    float z = 0.0f;
#pragma unroll
    for (int k = 0; k < 8; ++k) z += zred[k];
    Zpart[bx] = z;
  }
}

// Kernel 3: the permute, output-centric. Block owns 32 consecutive OUTPUT
// positions: gathered cached reads (16 independent loads in flight/thread),
// streaming 64 KB contiguous writes. Positions >= NKEEP accumulate
// w-weighted rows into partial slabs. grid (128, NB) x 256.
__global__ void __launch_bounds__(256) k_perm(const f32x4* __restrict__ tok,
                                              const int* __restrict__ order,
                                              const float* __restrict__ w,
                                              f32x4* __restrict__ sel,
                                              f32x4* __restrict__ partial) {
  int b = blockIdx.y;
  int bx = blockIdx.x;
  int p0 = bx * 32;
  int tid = threadIdx.x;
  int col = tid & 127;
  int g = tid >> 7;            // rows p0+g*16 .. p0+g*16+15
  __shared__ int ssrc[32];
  __shared__ float swt[32];
  __shared__ float accsh[512];
  if (tid < 32) {
    int p = p0 + tid;
    int src = order[b * NL + p];
    ssrc[tid] = src;
    swt[tid] = w[b * NL + src];    // 0 for keep rows
  }
  __syncthreads();

  const f32x4* tb = tok + (size_t)b * NL * NC4 + col;
  f32x4 v[16];
#pragma unroll
  for (int k = 0; k < 16; ++k)
    v[k] = tb[(size_t)ssrc[g * 16 + k] * NC4];

  f32x4* sb = sel + (size_t)b * NKEEP * NC4 + col;
  float a0 = 0.f, a1 = 0.f, a2 = 0.f, a3 = 0.f;
#pragma unroll
  for (int k = 0; k < 16; ++k) {
    int p = p0 + g * 16 + k;
    if (p < NKEEP) {
      sb[(size_t)p * NC4] = v[k];          // streaming contiguous writes
    } else {
      float wk = swt[g * 16 + k];
      a0 = fmaf(wk, v[k].x, a0);
      a1 = fmaf(wk, v[k].y, a1);
      a2 = fmaf(wk, v[k].z, a2);
      a3 = fmaf(wk, v[k].w, a3);
    }
  }

  if (bx >= KEEPB) {                        // uniform per block
    if (g == 1) {
      accsh[col * 4 + 0] = a0; accsh[col * 4 + 1] = a1;
      accsh[col * 4 + 2] = a2; accsh[col * 4 + 3] = a3;
    }
    __syncthreads();
    if (g == 0) {
      f32x4 o;
      o.x = a0 + accsh[col * 4 + 0];
      o.y = a1 + accsh[col * 4 + 1];
      o.z = a2 + accsh[col * 4 + 2];
      o.w = a3 + accsh[col * 4 + 3];
      partial[(size_t)(b * NTAILB + (bx - KEEPB)) * 128 + col] = o;
    }
  }
}

// Kernel 4: extra = (sum of 52 partials) / (sum of 8 Z partials). 16 x 512.
__global__ void __launch_bounds__(512) k_back(const float* __restrict__ partial,
                                              const float* __restrict__ Zpart,
                                              float* __restrict__ extra) {
  int b = blockIdx.x;
  int c = threadIdx.x;    // 0..511
  float Zb = 0.0f;
#pragma unroll
  for (int k = 0; k < 8; ++k) Zb += Zpart[b * 8 + k];
  const float* p = partial + (size_t)b * NTAILB * 512 + c;
  float a0 = 0.f, a1 = 0.f, a2 = 0.f, a3 = 0.f;
#pragma unroll
  for (int j = 0; j < NTAILB; j += 4) {
    a0 += p[(size_t)(j + 0) * 512];
    a1 += p[(size_t)(j + 1) * 512];
    a2 += p[(size_t)(j + 2) * 512];
    a3 += p[(size_t)(j + 3) * 512];
  }
  extra[b * NC + c] = ((a0 + a1) + (a2 + a3)) / Zb;
}

extern "C" void kernel_launch(void* const* d_in, const int* in_sizes, int n_in,
                              void* d_out, int out_size, void* d_ws, size_t ws_size,
                              hipStream_t stream) {
  (void)in_sizes; (void)n_in; (void)out_size; (void)ws_size;
  const f32x4* tok = (const f32x4*)d_in[0];
  const float* ax = (const float*)d_in[1];
  const float* ay = (const float*)d_in[2];

  unsigned long long* skey = (unsigned long long*)d_ws;
  float* w = (float*)((char*)d_ws + 524288);
  int* order = (int*)((char*)d_ws + 786432);
  f32x4* partial = (f32x4*)((char*)d_ws + 1048576);
  float* Zpart = (float*)((char*)d_ws + 2883584);

  float* out = (float*)d_out;
  f32x4* sel = (f32x4*)out;                         // [16][2458][512]
  float* extra = out + (size_t)NB * NKEEP * NC;     // [16][1][512]
  float* mask = extra + (size_t)NB * NC;            // [16][4096]

  k_sort<<<dim3(8, NB), 256, 0, stream>>>(ax, ay, skey);
  k_mid<<<128, 512, 0, stream>>>(ax, ay, skey, w, mask, order, Zpart);
  k_perm<<<dim3(128, NB), 256, 0, stream>>>(tok, order, w, sel, partial);
  k_back<<<NB, 512, 0, stream>>>((const float*)partial, Zpart, extra);
}